// Round 9
// baseline (595.094 us; speedup 1.0000x reference)
//
#include <hip/hip_runtime.h>
#include <math.h>

#define HW 4096
#define FIXUP_THR 4e-3f

typedef _Float16 half8_t __attribute__((ext_vector_type(8)));
typedef _Float16 half4_t __attribute__((ext_vector_type(4)));
typedef float f32x4 __attribute__((ext_vector_type(4)));

// ------- merged per-batch transpose to fp16 + per-position sumsq partials -------
__global__ __launch_bounds__(256) void transpose_b(
    const float* __restrict__ s3f, const float* __restrict__ t3f,
    const float* __restrict__ s4f, const float* __restrict__ t4f,
    _Float16* __restrict__ P, float* __restrict__ part, int b) {
    __shared__ float tile[64][65];
    const int t = threadIdx.x;
    int blk = blockIdx.x;
    const float* f;
    _Float16* out;
    float* pt;
    int C;
    if (blk < 2048) {
        C = 1024;
        if (blk < 1024) { f = t3f; out = P;            pt = part;          }
        else            { f = s3f; out = P + 4194304;  pt = part + 65536;  blk -= 1024; }
    } else {
        C = 2048;
        if (blk < 4096) { f = t4f; out = P + 8388608;  pt = part + 131072; blk -= 2048; }
        else            { f = s4f; out = P + 16777216; pt = part + 262144; blk -= 4096; }
    }
    const int p0 = (blk & 63) * 64;
    const int c0 = (blk >> 6) * 64;
    const int cblk = blk >> 6;
    const float* src = f + ((size_t)b * C + c0) * HW + p0;
    {
        const int cl = t >> 4;
        const int pl = (t & 15) * 4;
#pragma unroll
        for (int it = 0; it < 4; ++it) {
            float4 v = *(const float4*)(src + (size_t)(cl + it * 16) * HW + pl);
            tile[cl + it * 16][pl + 0] = v.x;
            tile[cl + it * 16][pl + 1] = v.y;
            tile[cl + it * 16][pl + 2] = v.z;
            tile[cl + it * 16][pl + 3] = v.w;
        }
    }
    __syncthreads();
    const int pr = t >> 3;
    const int cb = (t & 7) * 8;
#pragma unroll
    for (int it = 0; it < 2; ++it) {
        const int p = pr + it * 32;
        union { _Float16 h[8]; float4 v4; } H;
        float ssq = 0.f;
#pragma unroll
        for (int u = 0; u < 8; ++u) {
            float v = tile[cb + u][p];
            H.h[u] = (_Float16)v;
            ssq = fmaf(v, v, ssq);
        }
        *(float4*)(out + (size_t)(p0 + p) * C + c0 + cb) = H.v4;
        ssq += __shfl_down(ssq, 4);
        ssq += __shfl_down(ssq, 2);
        ssq += __shfl_down(ssq, 1);
        if ((t & 7) == 0) pt[(size_t)cblk * 4096 + p0 + p] = ssq;
    }
}

// part order: t3 | s3 | t4 | s4 ; inv order: s3 | t3 | s4 | t4 (8192 apart, [b*4096+pos])
__global__ __launch_bounds__(256) void norm_finalize_b(const float* __restrict__ part,
                                                       float* __restrict__ inv, int b) {
    const int idx = blockIdx.x * 256 + threadIdx.x;   // 0..16383
    const int tensor = idx >> 12;
    const int pos = idx & 4095;
    const int nblk[4] = {16, 16, 32, 32};
    const int poff[4] = {0, 65536, 131072, 262144};
    const int ivoff[4] = {8192, 0, 24576, 16384};
    const float* pt = part + poff[tensor] + pos;
    float s = 0.f;
    const int n = nblk[tensor];
    for (int k = 0; k < n; ++k) s += pt[(size_t)k * 4096];
    inv[ivoff[tensor] + b * 4096 + pos] = 1.0f / sqrtf(s + 1e-6f);
}

// ---------------- fused dual-level fp16 MFMA correlation GEMM, per batch ----------------
// M[b,j,i] = relu(dot3*n3) * relu(dot4*n4)  (fp16), MT[b,i,j] = M[b,j,i]
// 2-phase double-buffered LDS; XCD-chunked block swizzle (1024 blocks % 8 == 0:
// XCD k gets contiguous output chunk -> its A panels fit the 4 MB per-XCD L2).
__global__ __launch_bounds__(256, 2) void corr_fused(
    const _Float16* __restrict__ A3, const _Float16* __restrict__ B3,
    const _Float16* __restrict__ A4, const _Float16* __restrict__ B4,
    const float* __restrict__ invA3, const float* __restrict__ invB3,
    const float* __restrict__ invA4, const float* __restrict__ invB4,
    _Float16* __restrict__ M, _Float16* __restrict__ MT, int b) {
    __shared__ char lds[65536];   // 2 x (A tile 128x64 fp16 16KB | B tile 16KB)
    const int tid = threadIdx.x;
    const int bid = blockIdx.x;                      // 0..1023
    const int swz = (bid & 7) * 128 + (bid >> 3);    // XCD-chunked, bijective
    const int i0 = (swz & 31) * 128;
    const int j0 = (swz >> 5) * 128;
    const int lane = tid & 63;
    const int w = tid >> 6;
    const int wj = (w >> 1) * 64, wi = (w & 1) * 64;
    const int quad = lane >> 4;

    int offA[2][4], offB[2][4];
#pragma unroll
    for (int f = 0; f < 4; ++f) {
        int jr = wj + f * 16 + (lane & 15);
        int baseA = jr * 128 + ((quad ^ (jr & 3)) << 4);
        int xkA = ((jr >> 2) & 1) << 6;
        offA[0][f] = baseA + xkA;
        offA[1][f] = baseA + (64 ^ xkA);
        int ir = wi + f * 16 + (lane & 15);
        int baseB = 16384 + ir * 128 + ((quad ^ (ir & 3)) << 4);
        int xkB = ((ir >> 2) & 1) << 6;
        offB[0][f] = baseB + xkB;
        offB[1][f] = baseB + (64 ^ xkB);
    }

    int srow[8], selem[8];
#pragma unroll
    for (int s = 0; s < 8; ++s) {
        int g = s * 256 + tid;
        srow[s] = (g >> 3) & 127;
        selem[s] = ((g & 7) ^ (srow[s] & 7)) << 3;
    }

    const _Float16* s3p[8];
    const _Float16* s4p[8];
#pragma unroll
    for (int s = 0; s < 8; ++s) {
        if (s < 4) {
            s3p[s] = A3 + (size_t)(j0 + srow[s]) * 1024 + selem[s];
            s4p[s] = A4 + (size_t)(j0 + srow[s]) * 2048 + selem[s];
        } else {
            s3p[s] = B3 + (size_t)(i0 + srow[s]) * 1024 + selem[s];
            s4p[s] = B4 + (size_t)(i0 + srow[s]) * 2048 + selem[s];
        }
    }

    half4_t v3p[4][4];
    f32x4 acc[4][4] = {};

    auto stage = [&](int buf, const _Float16** sp) {
#pragma unroll
        for (int s = 0; s < 8; ++s) {
            __builtin_amdgcn_global_load_lds(
                (const __attribute__((address_space(1))) void*)(sp[s]),
                (__attribute__((address_space(3))) void*)(lds + (buf << 15) +
                                                          (s * 256 + tid) * 16),
                16, 0, 0);
            sp[s] += 64;
        }
    };
    auto compute = [&](int buf) {
        const int bo = buf << 15;
#pragma unroll
        for (int st = 0; st < 2; ++st) {
            half8_t a[4], bb[4];
#pragma unroll
            for (int f = 0; f < 4; ++f) {
                a[f] = *(const half8_t*)(lds + bo + offA[st][f]);
                bb[f] = *(const half8_t*)(lds + bo + offB[st][f]);
            }
#pragma unroll
            for (int fy = 0; fy < 4; ++fy)
#pragma unroll
                for (int fx = 0; fx < 4; ++fx)
                    acc[fy][fx] = __builtin_amdgcn_mfma_f32_16x16x32_f16(
                        a[fy], bb[fx], acc[fy][fx], 0, 0, 0);
        }
    };

    stage(0, s3p);
    __syncthreads();
    int cur = 0;
#pragma unroll 1
    for (int kt = 0; kt < 16; ++kt) {
        if (kt < 15) stage(cur ^ 1, s3p);
        else         stage(cur ^ 1, s4p);    // cross-phase prefetch: level-4 tile 0
        compute(cur);
        __syncthreads();
        cur ^= 1;
    }

    // ph0 epilogue: stash relu(corr3) as fp16, reset acc (registers only)
    {
        const int ib = i0 + wi + (lane & 15);
        float sB[4];
#pragma unroll
        for (int fx = 0; fx < 4; ++fx) sB[fx] = invB3[b * 4096 + ib + fx * 16];
#pragma unroll
        for (int fy = 0; fy < 4; ++fy) {
            const int jb = j0 + wj + fy * 16 + quad * 4;
            float sA[4];
#pragma unroll
            for (int r = 0; r < 4; ++r) sA[r] = invA3[b * 4096 + jb + r];
#pragma unroll
            for (int fx = 0; fx < 4; ++fx)
#pragma unroll
                for (int r = 0; r < 4; ++r) {
                    v3p[fy][fx][r] =
                        (_Float16)fmaxf(acc[fy][fx][r] * sA[r] * sB[fx], 0.f);
                    acc[fy][fx][r] = 0.f;
                }
        }
    }

#pragma unroll 1
    for (int kt = 0; kt < 32; ++kt) {
        if (kt < 31) stage(cur ^ 1, s4p);
        compute(cur);
        __syncthreads();
        cur ^= 1;
    }

    const int ib = i0 + wi + (lane & 15);
    float sB[4];
#pragma unroll
    for (int fx = 0; fx < 4; ++fx) sB[fx] = invB4[b * 4096 + ib + fx * 16];
#pragma unroll
    for (int fy = 0; fy < 4; ++fy) {
        const int jb = j0 + wj + fy * 16 + quad * 4;
        float sA[4];
#pragma unroll
        for (int r = 0; r < 4; ++r) sA[r] = invA4[b * 4096 + jb + r];
#pragma unroll
        for (int fx = 0; fx < 4; ++fx) {
            const int ii = ib + fx * 16;
            union { _Float16 h[4]; double d; } pk;
#pragma unroll
            for (int r = 0; r < 4; ++r) {
                float v = fmaxf(acc[fy][fx][r] * sA[r] * sB[fx], 0.f) *
                          (float)v3p[fy][fx][r];
                M[((size_t)b * HW + (jb + r)) * HW + ii] = (_Float16)v;
                pk.h[r] = (_Float16)v;
            }
            *(double*)(MT + ((size_t)b * HW + ii) * HW + jb) = pk.d;
        }
    }
}

// ---------------- fused per-line soft-argmax (z = colmode) ----------------
// Key-packed top-2 (monotone u32 key = (fp16bits<<12)|(4095-j)); fixup candidates
// parallelized ACROSS WAVES: each wave computes a full 3072-dot alone (64-lane
// partition + butterfly, zero block barriers in the candidate loop), per-wave bests
// merged once in fixed order — kills the serial-fixup tail.
__global__ __launch_bounds__(256, 6) void soft_argmax(
    const _Float16* __restrict__ M, const _Float16* __restrict__ MT,
    float* __restrict__ out,
    const float* __restrict__ s3, const float* __restrict__ t3,
    const float* __restrict__ s4, const float* __restrict__ t4,
    const float* __restrict__ inv) {
    __shared__ float lf[3072];                       // fixup-only line features (12 KB)
    __shared__ __align__(16) float gtab[128];        // gx[0..63] | gy[64..127]
    __shared__ float wsS[4], wsA[4], wsB[4], wsC[4];
    __shared__ unsigned wsK1[4], wsK2[4];
    __shared__ int cnd[64];
    __shared__ int ncnd;
    const int tid = threadIdx.x;
    const int lane = tid & 63;
    const int wv = tid >> 6;
    const int b = blockIdx.y;
    const int line = blockIdx.x;
    const int colmode = blockIdx.z;

    const float* cf3 = colmode ? t3 : s3;
    const float* lf3 = colmode ? s3 : t3;
    const float* cf4 = colmode ? t4 : s4;
    const float* lf4 = colmode ? s4 : t4;
    const float* invc3 = inv + (colmode ? 8192 : 0);
    const float* invl3 = inv + (colmode ? 0 : 8192);
    const float* invc4 = inv + (colmode ? 24576 : 16384);
    const float* invl4 = inv + (colmode ? 16384 : 24576);

    const _Float16* src = (colmode ? MT : M) + ((size_t)b * HW + line) * HW;

    // ---- load row into registers; pass 1: sumsq + key-packed top-2 ----
    union U { half8_t v; unsigned short s[8]; };
    U H[2];
    H[0].v = ((const half8_t*)src)[tid];
    H[1].v = ((const half8_t*)src)[tid + 256];

    float ss = 0.f;
    unsigned k1 = 0u, k2 = 0u;
#pragma unroll
    for (int it = 0; it < 2; ++it) {
        const unsigned invbase = 4095u - (unsigned)((tid + it * 256) * 8);
#pragma unroll
        for (int u = 0; u < 8; ++u) {
            float v = (float)H[it].v[u];
            ss = fmaf(v, v, ss);
            unsigned kk = ((unsigned)H[it].s[u] << 12) | (invbase - u);
            unsigned lo = min(kk, k1);
            k1 = max(kk, k1);
            k2 = max(k2, lo);
        }
    }
#pragma unroll
    for (int m = 1; m < 64; m <<= 1) {
        ss += __shfl_xor(ss, m);
        unsigned o1 = __shfl_xor(k1, m);
        unsigned o2 = __shfl_xor(k2, m);
        unsigned lo = min(k1, o1);
        k1 = max(k1, o1);
        k2 = max(max(k2, o2), lo);
    }
    if (lane == 0) { wsS[wv] = ss; wsK1[wv] = k1; wsK2[wv] = k2; }
    __syncthreads();
    // all threads merge the 4 wave partials in fixed order (identical everywhere)
    const float ssq = wsS[0] + wsS[1] + wsS[2] + wsS[3];
    unsigned K1 = wsK1[0], K2 = wsK2[0];
#pragma unroll
    for (int k = 1; k < 4; ++k) {
        unsigned o1 = wsK1[k], o2 = wsK2[k];
        unsigned lo = min(K1, o1);
        K1 = max(K1, o1);
        K2 = max(max(K2, o2), lo);
    }
    union HB { unsigned short u; _Float16 h; };
    HB hb1, hb2;
    hb1.u = (unsigned short)(K1 >> 12);
    hb2.u = (unsigned short)(K2 >> 12);
    const float m1 = (float)hb1.h;
    const float m2 = (float)hb2.h;
    int amax = 4095 - (int)(K1 & 4095u);
    const float inv_l = 1.0f / sqrtf(ssq + 1e-6f);
    const float vmax = m1 * inv_l;

    // near-tie fixup (block-uniform branch): exact fp32 recompute of every candidate;
    // candidates distributed over the 4 waves, each wave reduces its dot alone.
    const float cut = m1 - FIXUP_THR * m1;
    if (m2 >= cut) {
        if (tid == 0) ncnd = 0;
        __syncthreads();
#pragma unroll
        for (int it = 0; it < 2; ++it)
#pragma unroll
            for (int u = 0; u < 8; ++u)
                if ((float)H[it].v[u] >= cut) {
                    int k = atomicAdd(&ncnd, 1);
                    if (k < 64) cnd[k] = (tid + it * 256) * 8 + u;
                }
        for (int c = tid; c < 1024; c += 256)
            lf[c] = lf3[((size_t)b * 1024 + c) * HW + line];
        for (int c = tid; c < 2048; c += 256)
            lf[1024 + c] = lf4[((size_t)b * 2048 + c) * HW + line];
        __syncthreads();                      // cnd + lf visible to all waves
        const int nc = ncnd < 64 ? ncnd : 64;
        float bE = -1.f;
        int bI = 1 << 30;
#pragma unroll 1
        for (int k = wv; k < nc; k += 4) {
            const int jc = cnd[k];
            float d3 = 0.f, d4 = 0.f;
            for (int c = lane; c < 1024; c += 64)
                d3 = fmaf(cf3[((size_t)b * 1024 + c) * HW + jc], lf[c], d3);
            for (int c = lane; c < 2048; c += 64)
                d4 = fmaf(cf4[((size_t)b * 2048 + c) * HW + jc], lf[1024 + c], d4);
#pragma unroll
            for (int m = 1; m < 64; m <<= 1) {
                d3 += __shfl_xor(d3, m);
                d4 += __shfl_xor(d4, m);
            }
            float e3 = fmaxf(d3 * invc3[b * 4096 + jc] * invl3[b * 4096 + line], 0.f);
            float e4 = fmaxf(d4 * invc4[b * 4096 + jc] * invl4[b * 4096 + line], 0.f);
            float e = e3 * e4;
            if (e > bE || (e == bE && jc < bI)) { bE = e; bI = jc; }
        }
        if (lane == 0) { wsS[wv] = bE; wsK1[wv] = (unsigned)bI; }
        __syncthreads();
        float BE = wsS[0];
        int BI = (int)wsK1[0];
#pragma unroll
        for (int k = 1; k < 4; ++k) {
            float e = wsS[k];
            int jc = (int)wsK1[k];
            if (e > BE || (e == BE && jc < BI)) { BE = e; BI = jc; }
        }
        amax = BI;
    }

    const float ax = (float)(amax & 63);
    const float ay = (float)(amax >> 6);

    // separable gaussian tables: gx[x]=exp(-(x-ax)^2/(2*sigma^2)), gy likewise
    if (tid < 128) {
        float d = (float)(tid & 63) - ((tid < 64) ? ax : ay);
        gtab[tid] = __expf(-d * d * 0.02f);
    }
    __syncthreads();

    // pass 2: gaussian-masked softmax expectation (vmax >= masked max: safe shift)
    const float C = -50.0f * vmax;
    float se = 0.f, sx = 0.f, sy = 0.f;
#pragma unroll
    for (int it = 0; it < 2; ++it) {
        const int j8 = tid + it * 256;
        const int x0 = (j8 & 7) * 8;
        const int y2 = j8 >> 3;
        float4 ga = *(const float4*)&gtab[x0];
        float4 gb = *(const float4*)&gtab[x0 + 4];
        const float gxv[8] = {ga.x, ga.y, ga.z, ga.w, gb.x, gb.y, gb.z, gb.w};
        const float G = 50.0f * gtab[64 + y2] * inv_l;
        const float yn = fmaf((float)y2, 2.0f / 63.0f, -1.0f);
        float sec = 0.f;
#pragma unroll
        for (int u = 0; u < 8; ++u) {
            float t = gxv[u] * (float)H[it].v[u];
            float e = __expf(fmaf(t, G, C));               // beta = 50
            sec += e;
            sx = fmaf(e, fmaf((float)(x0 + u), 2.0f / 63.0f, -1.0f), sx);
        }
        se += sec;
        sy = fmaf(sec, yn, sy);
    }
#pragma unroll
    for (int m = 1; m < 64; m <<= 1) {
        se += __shfl_xor(se, m);
        sx += __shfl_xor(sx, m);
        sy += __shfl_xor(sy, m);
    }
    if (lane == 0) { wsA[wv] = se; wsB[wv] = sx; wsC[wv] = sy; }
    __syncthreads();
    if (tid == 0) {
        float S = wsA[0] + wsA[1] + wsA[2] + wsA[3];
        float X = wsB[0] + wsB[1] + wsB[2] + wsB[3];
        float Y = wsC[0] + wsC[1] + wsC[2] + wsC[3];
        float gx = X / S;
        float gy = Y / S;
        size_t gbase = colmode ? 0 : 32768;
        size_t fbase = colmode ? 16384 : 49152;
        size_t p = gbase + ((size_t)b * HW + line) * 2;
        out[p] = gx;
        out[p + 1] = gy;
        out[fbase + (size_t)(b * 2 + 0) * HW + line] = 0.f;
        out[fbase + (size_t)(b * 2 + 1) * HW + line] = 0.f;
    }
}

extern "C" void kernel_launch(void* const* d_in, const int* in_sizes, int n_in,
                              void* d_out, int out_size, void* d_ws, size_t ws_size,
                              hipStream_t stream) {
    const float* s3 = (const float*)d_in[0];
    const float* t3 = (const float*)d_in[1];
    const float* s4 = (const float*)d_in[2];
    const float* t4 = (const float*)d_in[3];
    float* out = (float*)d_out;
    char* base = (char*)d_ws;

    // ws layout (bytes):
    //   inv    [0, 131072)                    4 tensors x [b][4096] fp32
    //   part   [131072, 1703936)              norm partials (t3|s3|t4|s4)
    //   M16    [1703936, 68812800)            fp16 2x4096x4096
    //   MT16   [68812800, 135921664)          fp16 transpose
    //   planes [135921664, 186253312)         per-batch fp16: t3|s3|t4|s4
    float* inv = (float*)base;
    float* part = (float*)(base + 131072);
    _Float16* M16 = (_Float16*)(base + 1703936);
    _Float16* MT16 = (_Float16*)(base + 68812800);
    _Float16* P = (_Float16*)(base + 135921664);

    for (int b = 0; b < 2; ++b) {
        transpose_b<<<6144, 256, 0, stream>>>(s3, t3, s4, t4, P, part, b);
        norm_finalize_b<<<64, 256, 0, stream>>>(part, inv, b);
        corr_fused<<<1024, 256, 0, stream>>>(P, P + 4194304, P + 8388608, P + 16777216,
                                             inv + 8192, inv + 0, inv + 24576, inv + 16384,
                                             M16, MT16, b);
    }

    dim3 rg(4096, 2, 2);
    soft_argmax<<<rg, 256, 0, stream>>>(M16, MT16, out, s3, t3, s4, t4, inv);
}

// Round 10
// 559.624 us; speedup vs baseline: 1.0634x; 1.0634x over previous
//
#include <hip/hip_runtime.h>
#include <math.h>

#define HW 4096
#define FIXUP_THR 4e-3f

typedef _Float16 half8_t __attribute__((ext_vector_type(8)));
typedef _Float16 half4_t __attribute__((ext_vector_type(4)));
typedef float f32x4 __attribute__((ext_vector_type(4)));

// ------- merged per-batch transpose to fp16 + per-position sumsq partials -------
__global__ __launch_bounds__(256) void transpose_b(
    const float* __restrict__ s3f, const float* __restrict__ t3f,
    const float* __restrict__ s4f, const float* __restrict__ t4f,
    _Float16* __restrict__ P, float* __restrict__ part, int b) {
    __shared__ float tile[64][65];
    const int t = threadIdx.x;
    int blk = blockIdx.x;
    const float* f;
    _Float16* out;
    float* pt;
    int C;
    if (blk < 2048) {
        C = 1024;
        if (blk < 1024) { f = t3f; out = P;            pt = part;          }
        else            { f = s3f; out = P + 4194304;  pt = part + 65536;  blk -= 1024; }
    } else {
        C = 2048;
        if (blk < 4096) { f = t4f; out = P + 8388608;  pt = part + 131072; blk -= 2048; }
        else            { f = s4f; out = P + 16777216; pt = part + 262144; blk -= 4096; }
    }
    const int p0 = (blk & 63) * 64;
    const int c0 = (blk >> 6) * 64;
    const int cblk = blk >> 6;
    const float* src = f + ((size_t)b * C + c0) * HW + p0;
    {
        const int cl = t >> 4;
        const int pl = (t & 15) * 4;
#pragma unroll
        for (int it = 0; it < 4; ++it) {
            float4 v = *(const float4*)(src + (size_t)(cl + it * 16) * HW + pl);
            tile[cl + it * 16][pl + 0] = v.x;
            tile[cl + it * 16][pl + 1] = v.y;
            tile[cl + it * 16][pl + 2] = v.z;
            tile[cl + it * 16][pl + 3] = v.w;
        }
    }
    __syncthreads();
    const int pr = t >> 3;
    const int cb = (t & 7) * 8;
#pragma unroll
    for (int it = 0; it < 2; ++it) {
        const int p = pr + it * 32;
        union { _Float16 h[8]; float4 v4; } H;
        float ssq = 0.f;
#pragma unroll
        for (int u = 0; u < 8; ++u) {
            float v = tile[cb + u][p];
            H.h[u] = (_Float16)v;
            ssq = fmaf(v, v, ssq);
        }
        *(float4*)(out + (size_t)(p0 + p) * C + c0 + cb) = H.v4;
        ssq += __shfl_down(ssq, 4);
        ssq += __shfl_down(ssq, 2);
        ssq += __shfl_down(ssq, 1);
        if ((t & 7) == 0) pt[(size_t)cblk * 4096 + p0 + p] = ssq;
    }
}

// part order: t3 | s3 | t4 | s4 ; inv order: s3 | t3 | s4 | t4 (8192 apart, [b*4096+pos])
__global__ __launch_bounds__(256) void norm_finalize_b(const float* __restrict__ part,
                                                       float* __restrict__ inv, int b) {
    const int idx = blockIdx.x * 256 + threadIdx.x;   // 0..16383
    const int tensor = idx >> 12;
    const int pos = idx & 4095;
    const int nblk[4] = {16, 16, 32, 32};
    const int poff[4] = {0, 65536, 131072, 262144};
    const int ivoff[4] = {8192, 0, 24576, 16384};
    const float* pt = part + poff[tensor] + pos;
    float s = 0.f;
    const int n = nblk[tensor];
    for (int k = 0; k < n; ++k) s += pt[(size_t)k * 4096];
    inv[ivoff[tensor] + b * 4096 + pos] = 1.0f / sqrtf(s + 1e-6f);
}

// ---------------- fused dual-level fp16 MFMA correlation GEMM, per batch ----------------
// M[b,j,i] = relu(dot3*n3) * relu(dot4*n4)  (fp16), MT[b,i,j] = M[b,j,i]
// 2-phase double-buffered LDS; natural 2D grid (x-fastest dispatch round-robins the
// B-row axis across XCDs -> per-XCD B working set ~2 MB, L2-fits; R9's chunked
// swizzle inflated it to full-B and doubled FETCH — do not reintroduce).
__global__ __launch_bounds__(256, 2) void corr_fused(
    const _Float16* __restrict__ A3, const _Float16* __restrict__ B3,
    const _Float16* __restrict__ A4, const _Float16* __restrict__ B4,
    const float* __restrict__ invA3, const float* __restrict__ invB3,
    const float* __restrict__ invA4, const float* __restrict__ invB4,
    _Float16* __restrict__ M, _Float16* __restrict__ MT, int b) {
    __shared__ char lds[65536];   // 2 x (A tile 128x64 fp16 16KB | B tile 16KB)
    const int tid = threadIdx.x;
    const int i0 = blockIdx.x * 128;
    const int j0 = blockIdx.y * 128;
    const int lane = tid & 63;
    const int w = tid >> 6;
    const int wj = (w >> 1) * 64, wi = (w & 1) * 64;
    const int quad = lane >> 4;

    int offA[2][4], offB[2][4];
#pragma unroll
    for (int f = 0; f < 4; ++f) {
        int jr = wj + f * 16 + (lane & 15);
        int baseA = jr * 128 + ((quad ^ (jr & 3)) << 4);
        int xkA = ((jr >> 2) & 1) << 6;
        offA[0][f] = baseA + xkA;
        offA[1][f] = baseA + (64 ^ xkA);
        int ir = wi + f * 16 + (lane & 15);
        int baseB = 16384 + ir * 128 + ((quad ^ (ir & 3)) << 4);
        int xkB = ((ir >> 2) & 1) << 6;
        offB[0][f] = baseB + xkB;
        offB[1][f] = baseB + (64 ^ xkB);
    }

    int srow[8], selem[8];
#pragma unroll
    for (int s = 0; s < 8; ++s) {
        int g = s * 256 + tid;
        srow[s] = (g >> 3) & 127;
        selem[s] = ((g & 7) ^ (srow[s] & 7)) << 3;
    }

    const _Float16* s3p[8];
    const _Float16* s4p[8];
#pragma unroll
    for (int s = 0; s < 8; ++s) {
        if (s < 4) {
            s3p[s] = A3 + (size_t)(j0 + srow[s]) * 1024 + selem[s];
            s4p[s] = A4 + (size_t)(j0 + srow[s]) * 2048 + selem[s];
        } else {
            s3p[s] = B3 + (size_t)(i0 + srow[s]) * 1024 + selem[s];
            s4p[s] = B4 + (size_t)(i0 + srow[s]) * 2048 + selem[s];
        }
    }

    half4_t v3p[4][4];
    f32x4 acc[4][4] = {};

    auto stage = [&](int buf, const _Float16** sp) {
#pragma unroll
        for (int s = 0; s < 8; ++s) {
            __builtin_amdgcn_global_load_lds(
                (const __attribute__((address_space(1))) void*)(sp[s]),
                (__attribute__((address_space(3))) void*)(lds + (buf << 15) +
                                                          (s * 256 + tid) * 16),
                16, 0, 0);
            sp[s] += 64;
        }
    };
    auto compute = [&](int buf) {
        const int bo = buf << 15;
#pragma unroll
        for (int st = 0; st < 2; ++st) {
            half8_t a[4], bb[4];
#pragma unroll
            for (int f = 0; f < 4; ++f) {
                a[f] = *(const half8_t*)(lds + bo + offA[st][f]);
                bb[f] = *(const half8_t*)(lds + bo + offB[st][f]);
            }
#pragma unroll
            for (int fy = 0; fy < 4; ++fy)
#pragma unroll
                for (int fx = 0; fx < 4; ++fx)
                    acc[fy][fx] = __builtin_amdgcn_mfma_f32_16x16x32_f16(
                        a[fy], bb[fx], acc[fy][fx], 0, 0, 0);
        }
    };

    stage(0, s3p);
    __syncthreads();
    int cur = 0;
#pragma unroll 1
    for (int kt = 0; kt < 16; ++kt) {
        if (kt < 15) stage(cur ^ 1, s3p);
        else         stage(cur ^ 1, s4p);    // cross-phase prefetch: level-4 tile 0
        compute(cur);
        __syncthreads();
        cur ^= 1;
    }

    // ph0 epilogue: stash relu(corr3) as fp16, reset acc (registers only)
    {
        const int ib = i0 + wi + (lane & 15);
        float sB[4];
#pragma unroll
        for (int fx = 0; fx < 4; ++fx) sB[fx] = invB3[b * 4096 + ib + fx * 16];
#pragma unroll
        for (int fy = 0; fy < 4; ++fy) {
            const int jb = j0 + wj + fy * 16 + quad * 4;
            float sA[4];
#pragma unroll
            for (int r = 0; r < 4; ++r) sA[r] = invA3[b * 4096 + jb + r];
#pragma unroll
            for (int fx = 0; fx < 4; ++fx)
#pragma unroll
                for (int r = 0; r < 4; ++r) {
                    v3p[fy][fx][r] =
                        (_Float16)fmaxf(acc[fy][fx][r] * sA[r] * sB[fx], 0.f);
                    acc[fy][fx][r] = 0.f;
                }
        }
    }

#pragma unroll 1
    for (int kt = 0; kt < 32; ++kt) {
        if (kt < 31) stage(cur ^ 1, s4p);
        compute(cur);
        __syncthreads();
        cur ^= 1;
    }

    const int ib = i0 + wi + (lane & 15);
    float sB[4];
#pragma unroll
    for (int fx = 0; fx < 4; ++fx) sB[fx] = invB4[b * 4096 + ib + fx * 16];
#pragma unroll
    for (int fy = 0; fy < 4; ++fy) {
        const int jb = j0 + wj + fy * 16 + quad * 4;
        float sA[4];
#pragma unroll
        for (int r = 0; r < 4; ++r) sA[r] = invA4[b * 4096 + jb + r];
#pragma unroll
        for (int fx = 0; fx < 4; ++fx) {
            const int ii = ib + fx * 16;
            union { _Float16 h[4]; double d; } pk;
#pragma unroll
            for (int r = 0; r < 4; ++r) {
                float v = fmaxf(acc[fy][fx][r] * sA[r] * sB[fx], 0.f) *
                          (float)v3p[fy][fx][r];
                M[((size_t)b * HW + (jb + r)) * HW + ii] = (_Float16)v;
                pk.h[r] = (_Float16)v;
            }
            *(double*)(MT + ((size_t)b * HW + ii) * HW + jb) = pk.d;
        }
    }
}

// ---------------- fused per-line soft-argmax (z = colmode) ----------------
// Key-packed top-2 (monotone u32 key = (fp16bits<<12)|(4095-j)); fixup candidates
// parallelized ACROSS WAVES: each wave computes a full 3072-dot alone (64-lane
// partition + butterfly, zero block barriers in the candidate loop), per-wave bests
// merged once in fixed order — kills the serial-fixup tail.
__global__ __launch_bounds__(256, 6) void soft_argmax(
    const _Float16* __restrict__ M, const _Float16* __restrict__ MT,
    float* __restrict__ out,
    const float* __restrict__ s3, const float* __restrict__ t3,
    const float* __restrict__ s4, const float* __restrict__ t4,
    const float* __restrict__ inv) {
    __shared__ float lf[3072];                       // fixup-only line features (12 KB)
    __shared__ __align__(16) float gtab[128];        // gx[0..63] | gy[64..127]
    __shared__ float wsS[4], wsA[4], wsB[4], wsC[4];
    __shared__ unsigned wsK1[4], wsK2[4];
    __shared__ int cnd[64];
    __shared__ int ncnd;
    const int tid = threadIdx.x;
    const int lane = tid & 63;
    const int wv = tid >> 6;
    const int b = blockIdx.y;
    const int line = blockIdx.x;
    const int colmode = blockIdx.z;

    const float* cf3 = colmode ? t3 : s3;
    const float* lf3 = colmode ? s3 : t3;
    const float* cf4 = colmode ? t4 : s4;
    const float* lf4 = colmode ? s4 : t4;
    const float* invc3 = inv + (colmode ? 8192 : 0);
    const float* invl3 = inv + (colmode ? 0 : 8192);
    const float* invc4 = inv + (colmode ? 24576 : 16384);
    const float* invl4 = inv + (colmode ? 16384 : 24576);

    const _Float16* src = (colmode ? MT : M) + ((size_t)b * HW + line) * HW;

    // ---- load row into registers; pass 1: sumsq + key-packed top-2 ----
    union U { half8_t v; unsigned short s[8]; };
    U H[2];
    H[0].v = ((const half8_t*)src)[tid];
    H[1].v = ((const half8_t*)src)[tid + 256];

    float ss = 0.f;
    unsigned k1 = 0u, k2 = 0u;
#pragma unroll
    for (int it = 0; it < 2; ++it) {
        const unsigned invbase = 4095u - (unsigned)((tid + it * 256) * 8);
#pragma unroll
        for (int u = 0; u < 8; ++u) {
            float v = (float)H[it].v[u];
            ss = fmaf(v, v, ss);
            unsigned kk = ((unsigned)H[it].s[u] << 12) | (invbase - u);
            unsigned lo = min(kk, k1);
            k1 = max(kk, k1);
            k2 = max(k2, lo);
        }
    }
#pragma unroll
    for (int m = 1; m < 64; m <<= 1) {
        ss += __shfl_xor(ss, m);
        unsigned o1 = __shfl_xor(k1, m);
        unsigned o2 = __shfl_xor(k2, m);
        unsigned lo = min(k1, o1);
        k1 = max(k1, o1);
        k2 = max(max(k2, o2), lo);
    }
    if (lane == 0) { wsS[wv] = ss; wsK1[wv] = k1; wsK2[wv] = k2; }
    __syncthreads();
    // all threads merge the 4 wave partials in fixed order (identical everywhere)
    const float ssq = wsS[0] + wsS[1] + wsS[2] + wsS[3];
    unsigned K1 = wsK1[0], K2 = wsK2[0];
#pragma unroll
    for (int k = 1; k < 4; ++k) {
        unsigned o1 = wsK1[k], o2 = wsK2[k];
        unsigned lo = min(K1, o1);
        K1 = max(K1, o1);
        K2 = max(max(K2, o2), lo);
    }
    union HB { unsigned short u; _Float16 h; };
    HB hb1, hb2;
    hb1.u = (unsigned short)(K1 >> 12);
    hb2.u = (unsigned short)(K2 >> 12);
    const float m1 = (float)hb1.h;
    const float m2 = (float)hb2.h;
    int amax = 4095 - (int)(K1 & 4095u);
    const float inv_l = 1.0f / sqrtf(ssq + 1e-6f);
    const float vmax = m1 * inv_l;

    // near-tie fixup (block-uniform branch): exact fp32 recompute of every candidate;
    // candidates distributed over the 4 waves, each wave reduces its dot alone.
    const float cut = m1 - FIXUP_THR * m1;
    if (m2 >= cut) {
        if (tid == 0) ncnd = 0;
        __syncthreads();
#pragma unroll
        for (int it = 0; it < 2; ++it)
#pragma unroll
            for (int u = 0; u < 8; ++u)
                if ((float)H[it].v[u] >= cut) {
                    int k = atomicAdd(&ncnd, 1);
                    if (k < 64) cnd[k] = (tid + it * 256) * 8 + u;
                }
        for (int c = tid; c < 1024; c += 256)
            lf[c] = lf3[((size_t)b * 1024 + c) * HW + line];
        for (int c = tid; c < 2048; c += 256)
            lf[1024 + c] = lf4[((size_t)b * 2048 + c) * HW + line];
        __syncthreads();                      // cnd + lf visible to all waves
        const int nc = ncnd < 64 ? ncnd : 64;
        float bE = -1.f;
        int bI = 1 << 30;
#pragma unroll 1
        for (int k = wv; k < nc; k += 4) {
            const int jc = cnd[k];
            float d3 = 0.f, d4 = 0.f;
            for (int c = lane; c < 1024; c += 64)
                d3 = fmaf(cf3[((size_t)b * 1024 + c) * HW + jc], lf[c], d3);
            for (int c = lane; c < 2048; c += 64)
                d4 = fmaf(cf4[((size_t)b * 2048 + c) * HW + jc], lf[1024 + c], d4);
#pragma unroll
            for (int m = 1; m < 64; m <<= 1) {
                d3 += __shfl_xor(d3, m);
                d4 += __shfl_xor(d4, m);
            }
            float e3 = fmaxf(d3 * invc3[b * 4096 + jc] * invl3[b * 4096 + line], 0.f);
            float e4 = fmaxf(d4 * invc4[b * 4096 + jc] * invl4[b * 4096 + line], 0.f);
            float e = e3 * e4;
            if (e > bE || (e == bE && jc < bI)) { bE = e; bI = jc; }
        }
        if (lane == 0) { wsS[wv] = bE; wsK1[wv] = (unsigned)bI; }
        __syncthreads();
        float BE = wsS[0];
        int BI = (int)wsK1[0];
#pragma unroll
        for (int k = 1; k < 4; ++k) {
            float e = wsS[k];
            int jc = (int)wsK1[k];
            if (e > BE || (e == BE && jc < BI)) { BE = e; BI = jc; }
        }
        amax = BI;
    }

    const float ax = (float)(amax & 63);
    const float ay = (float)(amax >> 6);

    // separable gaussian tables: gx[x]=exp(-(x-ax)^2/(2*sigma^2)), gy likewise
    if (tid < 128) {
        float d = (float)(tid & 63) - ((tid < 64) ? ax : ay);
        gtab[tid] = __expf(-d * d * 0.02f);
    }
    __syncthreads();

    // pass 2: gaussian-masked softmax expectation (vmax >= masked max: safe shift)
    const float C = -50.0f * vmax;
    float se = 0.f, sx = 0.f, sy = 0.f;
#pragma unroll
    for (int it = 0; it < 2; ++it) {
        const int j8 = tid + it * 256;
        const int x0 = (j8 & 7) * 8;
        const int y2 = j8 >> 3;
        float4 ga = *(const float4*)&gtab[x0];
        float4 gb = *(const float4*)&gtab[x0 + 4];
        const float gxv[8] = {ga.x, ga.y, ga.z, ga.w, gb.x, gb.y, gb.z, gb.w};
        const float G = 50.0f * gtab[64 + y2] * inv_l;
        const float yn = fmaf((float)y2, 2.0f / 63.0f, -1.0f);
        float sec = 0.f;
#pragma unroll
        for (int u = 0; u < 8; ++u) {
            float t = gxv[u] * (float)H[it].v[u];
            float e = __expf(fmaf(t, G, C));               // beta = 50
            sec += e;
            sx = fmaf(e, fmaf((float)(x0 + u), 2.0f / 63.0f, -1.0f), sx);
        }
        se += sec;
        sy = fmaf(sec, yn, sy);
    }
#pragma unroll
    for (int m = 1; m < 64; m <<= 1) {
        se += __shfl_xor(se, m);
        sx += __shfl_xor(sx, m);
        sy += __shfl_xor(sy, m);
    }
    if (lane == 0) { wsA[wv] = se; wsB[wv] = sx; wsC[wv] = sy; }
    __syncthreads();
    if (tid == 0) {
        float S = wsA[0] + wsA[1] + wsA[2] + wsA[3];
        float X = wsB[0] + wsB[1] + wsB[2] + wsB[3];
        float Y = wsC[0] + wsC[1] + wsC[2] + wsC[3];
        float gx = X / S;
        float gy = Y / S;
        size_t gbase = colmode ? 0 : 32768;
        size_t fbase = colmode ? 16384 : 49152;
        size_t p = gbase + ((size_t)b * HW + line) * 2;
        out[p] = gx;
        out[p + 1] = gy;
        out[fbase + (size_t)(b * 2 + 0) * HW + line] = 0.f;
        out[fbase + (size_t)(b * 2 + 1) * HW + line] = 0.f;
    }
}

extern "C" void kernel_launch(void* const* d_in, const int* in_sizes, int n_in,
                              void* d_out, int out_size, void* d_ws, size_t ws_size,
                              hipStream_t stream) {
    const float* s3 = (const float*)d_in[0];
    const float* t3 = (const float*)d_in[1];
    const float* s4 = (const float*)d_in[2];
    const float* t4 = (const float*)d_in[3];
    float* out = (float*)d_out;
    char* base = (char*)d_ws;

    // ws layout (bytes):
    //   inv    [0, 131072)                    4 tensors x [b][4096] fp32
    //   part   [131072, 1703936)              norm partials (t3|s3|t4|s4)
    //   M16    [1703936, 68812800)            fp16 2x4096x4096
    //   MT16   [68812800, 135921664)          fp16 transpose
    //   planes [135921664, 186253312)         per-batch fp16: t3|s3|t4|s4
    float* inv = (float*)base;
    float* part = (float*)(base + 131072);
    _Float16* M16 = (_Float16*)(base + 1703936);
    _Float16* MT16 = (_Float16*)(base + 68812800);
    _Float16* P = (_Float16*)(base + 135921664);

    dim3 gg(32, 32);
    for (int b = 0; b < 2; ++b) {
        transpose_b<<<6144, 256, 0, stream>>>(s3, t3, s4, t4, P, part, b);
        norm_finalize_b<<<64, 256, 0, stream>>>(part, inv, b);
        corr_fused<<<gg, 256, 0, stream>>>(P, P + 4194304, P + 8388608, P + 16777216,
                                           inv + 8192, inv + 0, inv + 24576, inv + 16384,
                                           M16, MT16, b);
    }

    dim3 rg(4096, 2, 2);
    soft_argmax<<<rg, 256, 0, stream>>>(M16, MT16, out, s3, t3, s4, t4, inv);
}

// Round 11
// 549.620 us; speedup vs baseline: 1.0827x; 1.0182x over previous
//
#include <hip/hip_runtime.h>
#include <math.h>

#define HW 4096
#define FIXUP_THR 4e-3f

typedef _Float16 half8_t __attribute__((ext_vector_type(8)));
typedef _Float16 half4_t __attribute__((ext_vector_type(4)));
typedef float f32x4 __attribute__((ext_vector_type(4)));

// ------- merged per-batch transpose to fp16 + per-position sumsq partials -------
// Input reads are NON-TEMPORAL (read-exactly-once, 96 MB/batch): keeps them from
// evicting corr's M/MT output from L3 before soft_argmax consumes it.
__global__ __launch_bounds__(256) void transpose_b(
    const float* __restrict__ s3f, const float* __restrict__ t3f,
    const float* __restrict__ s4f, const float* __restrict__ t4f,
    _Float16* __restrict__ P, float* __restrict__ part, int b) {
    __shared__ float tile[64][65];
    const int t = threadIdx.x;
    int blk = blockIdx.x;
    const float* f;
    _Float16* out;
    float* pt;
    int C;
    if (blk < 2048) {
        C = 1024;
        if (blk < 1024) { f = t3f; out = P;            pt = part;          }
        else            { f = s3f; out = P + 4194304;  pt = part + 65536;  blk -= 1024; }
    } else {
        C = 2048;
        if (blk < 4096) { f = t4f; out = P + 8388608;  pt = part + 131072; blk -= 2048; }
        else            { f = s4f; out = P + 16777216; pt = part + 262144; blk -= 4096; }
    }
    const int p0 = (blk & 63) * 64;
    const int c0 = (blk >> 6) * 64;
    const int cblk = blk >> 6;
    const float* src = f + ((size_t)b * C + c0) * HW + p0;
    {
        const int cl = t >> 4;
        const int pl = (t & 15) * 4;
#pragma unroll
        for (int it = 0; it < 4; ++it) {
            f32x4 v = __builtin_nontemporal_load(
                (const f32x4*)(src + (size_t)(cl + it * 16) * HW + pl));
            tile[cl + it * 16][pl + 0] = v[0];
            tile[cl + it * 16][pl + 1] = v[1];
            tile[cl + it * 16][pl + 2] = v[2];
            tile[cl + it * 16][pl + 3] = v[3];
        }
    }
    __syncthreads();
    const int pr = t >> 3;
    const int cb = (t & 7) * 8;
#pragma unroll
    for (int it = 0; it < 2; ++it) {
        const int p = pr + it * 32;
        union { _Float16 h[8]; float4 v4; } H;
        float ssq = 0.f;
#pragma unroll
        for (int u = 0; u < 8; ++u) {
            float v = tile[cb + u][p];
            H.h[u] = (_Float16)v;
            ssq = fmaf(v, v, ssq);
        }
        *(float4*)(out + (size_t)(p0 + p) * C + c0 + cb) = H.v4;
        ssq += __shfl_down(ssq, 4);
        ssq += __shfl_down(ssq, 2);
        ssq += __shfl_down(ssq, 1);
        if ((t & 7) == 0) pt[(size_t)cblk * 4096 + p0 + p] = ssq;
    }
}

// part order: t3 | s3 | t4 | s4 ; inv order: s3 | t3 | s4 | t4 (8192 apart, [b*4096+pos])
__global__ __launch_bounds__(256) void norm_finalize_b(const float* __restrict__ part,
                                                       float* __restrict__ inv, int b) {
    const int idx = blockIdx.x * 256 + threadIdx.x;   // 0..16383
    const int tensor = idx >> 12;
    const int pos = idx & 4095;
    const int nblk[4] = {16, 16, 32, 32};
    const int poff[4] = {0, 65536, 131072, 262144};
    const int ivoff[4] = {8192, 0, 24576, 16384};
    const float* pt = part + poff[tensor] + pos;
    float s = 0.f;
    const int n = nblk[tensor];
    for (int k = 0; k < n; ++k) s += pt[(size_t)k * 4096];
    inv[ivoff[tensor] + b * 4096 + pos] = 1.0f / sqrtf(s + 1e-6f);
}

// ---------------- fused dual-level fp16 MFMA correlation GEMM, per batch ----------------
// M[b,j,i] = relu(dot3*n3) * relu(dot4*n4)  (fp16), MT[b,i,j] = M[b,j,i]
// 2-phase double-buffered LDS; natural 2D grid (x-fastest dispatch round-robins the
// B-row axis across XCDs -> per-XCD B working set ~2 MB, L2-fits; R9's chunked
// swizzle inflated it to full-B and doubled FETCH — do not reintroduce).
__global__ __launch_bounds__(256, 2) void corr_fused(
    const _Float16* __restrict__ A3, const _Float16* __restrict__ B3,
    const _Float16* __restrict__ A4, const _Float16* __restrict__ B4,
    const float* __restrict__ invA3, const float* __restrict__ invB3,
    const float* __restrict__ invA4, const float* __restrict__ invB4,
    _Float16* __restrict__ M, _Float16* __restrict__ MT, int b) {
    __shared__ char lds[65536];   // 2 x (A tile 128x64 fp16 16KB | B tile 16KB)
    const int tid = threadIdx.x;
    const int i0 = blockIdx.x * 128;
    const int j0 = blockIdx.y * 128;
    const int lane = tid & 63;
    const int w = tid >> 6;
    const int wj = (w >> 1) * 64, wi = (w & 1) * 64;
    const int quad = lane >> 4;

    int offA[2][4], offB[2][4];
#pragma unroll
    for (int f = 0; f < 4; ++f) {
        int jr = wj + f * 16 + (lane & 15);
        int baseA = jr * 128 + ((quad ^ (jr & 3)) << 4);
        int xkA = ((jr >> 2) & 1) << 6;
        offA[0][f] = baseA + xkA;
        offA[1][f] = baseA + (64 ^ xkA);
        int ir = wi + f * 16 + (lane & 15);
        int baseB = 16384 + ir * 128 + ((quad ^ (ir & 3)) << 4);
        int xkB = ((ir >> 2) & 1) << 6;
        offB[0][f] = baseB + xkB;
        offB[1][f] = baseB + (64 ^ xkB);
    }

    int srow[8], selem[8];
#pragma unroll
    for (int s = 0; s < 8; ++s) {
        int g = s * 256 + tid;
        srow[s] = (g >> 3) & 127;
        selem[s] = ((g & 7) ^ (srow[s] & 7)) << 3;
    }

    const _Float16* s3p[8];
    const _Float16* s4p[8];
#pragma unroll
    for (int s = 0; s < 8; ++s) {
        if (s < 4) {
            s3p[s] = A3 + (size_t)(j0 + srow[s]) * 1024 + selem[s];
            s4p[s] = A4 + (size_t)(j0 + srow[s]) * 2048 + selem[s];
        } else {
            s3p[s] = B3 + (size_t)(i0 + srow[s]) * 1024 + selem[s];
            s4p[s] = B4 + (size_t)(i0 + srow[s]) * 2048 + selem[s];
        }
    }

    half4_t v3p[4][4];
    f32x4 acc[4][4] = {};

    auto stage = [&](int buf, const _Float16** sp) {
#pragma unroll
        for (int s = 0; s < 8; ++s) {
            __builtin_amdgcn_global_load_lds(
                (const __attribute__((address_space(1))) void*)(sp[s]),
                (__attribute__((address_space(3))) void*)(lds + (buf << 15) +
                                                          (s * 256 + tid) * 16),
                16, 0, 0);
            sp[s] += 64;
        }
    };
    auto compute = [&](int buf) {
        const int bo = buf << 15;
#pragma unroll
        for (int st = 0; st < 2; ++st) {
            half8_t a[4], bb[4];
#pragma unroll
            for (int f = 0; f < 4; ++f) {
                a[f] = *(const half8_t*)(lds + bo + offA[st][f]);
                bb[f] = *(const half8_t*)(lds + bo + offB[st][f]);
            }
#pragma unroll
            for (int fy = 0; fy < 4; ++fy)
#pragma unroll
                for (int fx = 0; fx < 4; ++fx)
                    acc[fy][fx] = __builtin_amdgcn_mfma_f32_16x16x32_f16(
                        a[fy], bb[fx], acc[fy][fx], 0, 0, 0);
        }
    };

    stage(0, s3p);
    __syncthreads();
    int cur = 0;
#pragma unroll 1
    for (int kt = 0; kt < 16; ++kt) {
        if (kt < 15) stage(cur ^ 1, s3p);
        else         stage(cur ^ 1, s4p);    // cross-phase prefetch: level-4 tile 0
        compute(cur);
        __syncthreads();
        cur ^= 1;
    }

    // ph0 epilogue: stash relu(corr3) as fp16, reset acc (registers only)
    {
        const int ib = i0 + wi + (lane & 15);
        float sB[4];
#pragma unroll
        for (int fx = 0; fx < 4; ++fx) sB[fx] = invB3[b * 4096 + ib + fx * 16];
#pragma unroll
        for (int fy = 0; fy < 4; ++fy) {
            const int jb = j0 + wj + fy * 16 + quad * 4;
            float sA[4];
#pragma unroll
            for (int r = 0; r < 4; ++r) sA[r] = invA3[b * 4096 + jb + r];
#pragma unroll
            for (int fx = 0; fx < 4; ++fx)
#pragma unroll
                for (int r = 0; r < 4; ++r) {
                    v3p[fy][fx][r] =
                        (_Float16)fmaxf(acc[fy][fx][r] * sA[r] * sB[fx], 0.f);
                    acc[fy][fx][r] = 0.f;
                }
        }
    }

#pragma unroll 1
    for (int kt = 0; kt < 32; ++kt) {
        if (kt < 31) stage(cur ^ 1, s4p);
        compute(cur);
        __syncthreads();
        cur ^= 1;
    }

    const int ib = i0 + wi + (lane & 15);
    float sB[4];
#pragma unroll
    for (int fx = 0; fx < 4; ++fx) sB[fx] = invB4[b * 4096 + ib + fx * 16];
#pragma unroll
    for (int fy = 0; fy < 4; ++fy) {
        const int jb = j0 + wj + fy * 16 + quad * 4;
        float sA[4];
#pragma unroll
        for (int r = 0; r < 4; ++r) sA[r] = invA4[b * 4096 + jb + r];
#pragma unroll
        for (int fx = 0; fx < 4; ++fx) {
            const int ii = ib + fx * 16;
            union { _Float16 h[4]; double d; } pk;
#pragma unroll
            for (int r = 0; r < 4; ++r) {
                float v = fmaxf(acc[fy][fx][r] * sA[r] * sB[fx], 0.f) *
                          (float)v3p[fy][fx][r];
                M[((size_t)b * HW + (jb + r)) * HW + ii] = (_Float16)v;
                pk.h[r] = (_Float16)v;
            }
            *(double*)(MT + ((size_t)b * HW + ii) * HW + jb) = pk.d;
        }
    }
}

// ---------------- fused per-line soft-argmax (z = colmode) ----------------
// Key-packed top-2 (monotone u32 key = (fp16bits<<12)|(4095-j)); fixup candidates
// parallelized across waves (zero block barriers in the candidate loop).
__global__ __launch_bounds__(256, 6) void soft_argmax(
    const _Float16* __restrict__ M, const _Float16* __restrict__ MT,
    float* __restrict__ out,
    const float* __restrict__ s3, const float* __restrict__ t3,
    const float* __restrict__ s4, const float* __restrict__ t4,
    const float* __restrict__ inv) {
    __shared__ float lf[3072];                       // fixup-only line features (12 KB)
    __shared__ __align__(16) float gtab[128];        // gx[0..63] | gy[64..127]
    __shared__ float wsS[4], wsA[4], wsB[4], wsC[4];
    __shared__ unsigned wsK1[4], wsK2[4];
    __shared__ int cnd[64];
    __shared__ int ncnd;
    const int tid = threadIdx.x;
    const int lane = tid & 63;
    const int wv = tid >> 6;
    const int b = blockIdx.y;
    const int line = blockIdx.x;
    const int colmode = blockIdx.z;

    const float* cf3 = colmode ? t3 : s3;
    const float* lf3 = colmode ? s3 : t3;
    const float* cf4 = colmode ? t4 : s4;
    const float* lf4 = colmode ? s4 : t4;
    const float* invc3 = inv + (colmode ? 8192 : 0);
    const float* invl3 = inv + (colmode ? 0 : 8192);
    const float* invc4 = inv + (colmode ? 24576 : 16384);
    const float* invl4 = inv + (colmode ? 16384 : 24576);

    const _Float16* src = (colmode ? MT : M) + ((size_t)b * HW + line) * HW;

    // ---- load row into registers; pass 1: sumsq + key-packed top-2 ----
    union U { half8_t v; unsigned short s[8]; };
    U H[2];
    H[0].v = ((const half8_t*)src)[tid];
    H[1].v = ((const half8_t*)src)[tid + 256];

    float ss = 0.f;
    unsigned k1 = 0u, k2 = 0u;
#pragma unroll
    for (int it = 0; it < 2; ++it) {
        const unsigned invbase = 4095u - (unsigned)((tid + it * 256) * 8);
#pragma unroll
        for (int u = 0; u < 8; ++u) {
            float v = (float)H[it].v[u];
            ss = fmaf(v, v, ss);
            unsigned kk = ((unsigned)H[it].s[u] << 12) | (invbase - u);
            unsigned lo = min(kk, k1);
            k1 = max(kk, k1);
            k2 = max(k2, lo);
        }
    }
#pragma unroll
    for (int m = 1; m < 64; m <<= 1) {
        ss += __shfl_xor(ss, m);
        unsigned o1 = __shfl_xor(k1, m);
        unsigned o2 = __shfl_xor(k2, m);
        unsigned lo = min(k1, o1);
        k1 = max(k1, o1);
        k2 = max(max(k2, o2), lo);
    }
    if (lane == 0) { wsS[wv] = ss; wsK1[wv] = k1; wsK2[wv] = k2; }
    __syncthreads();
    // all threads merge the 4 wave partials in fixed order (identical everywhere)
    const float ssq = wsS[0] + wsS[1] + wsS[2] + wsS[3];
    unsigned K1 = wsK1[0], K2 = wsK2[0];
#pragma unroll
    for (int k = 1; k < 4; ++k) {
        unsigned o1 = wsK1[k], o2 = wsK2[k];
        unsigned lo = min(K1, o1);
        K1 = max(K1, o1);
        K2 = max(max(K2, o2), lo);
    }
    union HB { unsigned short u; _Float16 h; };
    HB hb1, hb2;
    hb1.u = (unsigned short)(K1 >> 12);
    hb2.u = (unsigned short)(K2 >> 12);
    const float m1 = (float)hb1.h;
    const float m2 = (float)hb2.h;
    int amax = 4095 - (int)(K1 & 4095u);
    const float inv_l = 1.0f / sqrtf(ssq + 1e-6f);
    const float vmax = m1 * inv_l;

    // near-tie fixup (block-uniform branch): exact fp32 recompute of every candidate;
    // candidates distributed over the 4 waves, each wave reduces its dot alone.
    const float cut = m1 - FIXUP_THR * m1;
    if (m2 >= cut) {
        if (tid == 0) ncnd = 0;
        __syncthreads();
#pragma unroll
        for (int it = 0; it < 2; ++it)
#pragma unroll
            for (int u = 0; u < 8; ++u)
                if ((float)H[it].v[u] >= cut) {
                    int k = atomicAdd(&ncnd, 1);
                    if (k < 64) cnd[k] = (tid + it * 256) * 8 + u;
                }
        for (int c = tid; c < 1024; c += 256)
            lf[c] = lf3[((size_t)b * 1024 + c) * HW + line];
        for (int c = tid; c < 2048; c += 256)
            lf[1024 + c] = lf4[((size_t)b * 2048 + c) * HW + line];
        __syncthreads();                      // cnd + lf visible to all waves
        const int nc = ncnd < 64 ? ncnd : 64;
        float bE = -1.f;
        int bI = 1 << 30;
#pragma unroll 1
        for (int k = wv; k < nc; k += 4) {
            const int jc = cnd[k];
            float d3 = 0.f, d4 = 0.f;
            for (int c = lane; c < 1024; c += 64)
                d3 = fmaf(cf3[((size_t)b * 1024 + c) * HW + jc], lf[c], d3);
            for (int c = lane; c < 2048; c += 64)
                d4 = fmaf(cf4[((size_t)b * 2048 + c) * HW + jc], lf[1024 + c], d4);
#pragma unroll
            for (int m = 1; m < 64; m <<= 1) {
                d3 += __shfl_xor(d3, m);
                d4 += __shfl_xor(d4, m);
            }
            float e3 = fmaxf(d3 * invc3[b * 4096 + jc] * invl3[b * 4096 + line], 0.f);
            float e4 = fmaxf(d4 * invc4[b * 4096 + jc] * invl4[b * 4096 + line], 0.f);
            float e = e3 * e4;
            if (e > bE || (e == bE && jc < bI)) { bE = e; bI = jc; }
        }
        if (lane == 0) { wsS[wv] = bE; wsK1[wv] = (unsigned)bI; }
        __syncthreads();
        float BE = wsS[0];
        int BI = (int)wsK1[0];
#pragma unroll
        for (int k = 1; k < 4; ++k) {
            float e = wsS[k];
            int jc = (int)wsK1[k];
            if (e > BE || (e == BE && jc < BI)) { BE = e; BI = jc; }
        }
        amax = BI;
    }

    const float ax = (float)(amax & 63);
    const float ay = (float)(amax >> 6);

    // separable gaussian tables: gx[x]=exp(-(x-ax)^2/(2*sigma^2)), gy likewise
    if (tid < 128) {
        float d = (float)(tid & 63) - ((tid < 64) ? ax : ay);
        gtab[tid] = __expf(-d * d * 0.02f);
    }
    __syncthreads();

    // pass 2: gaussian-masked softmax expectation (vmax >= masked max: safe shift)
    const float C = -50.0f * vmax;
    float se = 0.f, sx = 0.f, sy = 0.f;
#pragma unroll
    for (int it = 0; it < 2; ++it) {
        const int j8 = tid + it * 256;
        const int x0 = (j8 & 7) * 8;
        const int y2 = j8 >> 3;
        float4 ga = *(const float4*)&gtab[x0];
        float4 gb = *(const float4*)&gtab[x0 + 4];
        const float gxv[8] = {ga.x, ga.y, ga.z, ga.w, gb.x, gb.y, gb.z, gb.w};
        const float G = 50.0f * gtab[64 + y2] * inv_l;
        const float yn = fmaf((float)y2, 2.0f / 63.0f, -1.0f);
        float sec = 0.f;
#pragma unroll
        for (int u = 0; u < 8; ++u) {
            float t = gxv[u] * (float)H[it].v[u];
            float e = __expf(fmaf(t, G, C));               // beta = 50
            sec += e;
            sx = fmaf(e, fmaf((float)(x0 + u), 2.0f / 63.0f, -1.0f), sx);
        }
        se += sec;
        sy = fmaf(sec, yn, sy);
    }
#pragma unroll
    for (int m = 1; m < 64; m <<= 1) {
        se += __shfl_xor(se, m);
        sx += __shfl_xor(sx, m);
        sy += __shfl_xor(sy, m);
    }
    if (lane == 0) { wsA[wv] = se; wsB[wv] = sx; wsC[wv] = sy; }
    __syncthreads();
    if (tid == 0) {
        float S = wsA[0] + wsA[1] + wsA[2] + wsA[3];
        float X = wsB[0] + wsB[1] + wsB[2] + wsB[3];
        float Y = wsC[0] + wsC[1] + wsC[2] + wsC[3];
        float gx = X / S;
        float gy = Y / S;
        size_t gbase = colmode ? 0 : 32768;
        size_t fbase = colmode ? 16384 : 49152;
        size_t p = gbase + ((size_t)b * HW + line) * 2;
        out[p] = gx;
        out[p + 1] = gy;
        out[fbase + (size_t)(b * 2 + 0) * HW + line] = 0.f;
        out[fbase + (size_t)(b * 2 + 1) * HW + line] = 0.f;
    }
}

extern "C" void kernel_launch(void* const* d_in, const int* in_sizes, int n_in,
                              void* d_out, int out_size, void* d_ws, size_t ws_size,
                              hipStream_t stream) {
    const float* s3 = (const float*)d_in[0];
    const float* t3 = (const float*)d_in[1];
    const float* s4 = (const float*)d_in[2];
    const float* t4 = (const float*)d_in[3];
    float* out = (float*)d_out;
    char* base = (char*)d_ws;

    // ws layout (bytes):
    //   inv    [0, 131072)                    4 tensors x [b][4096] fp32
    //   part   [131072, 1703936)              norm partials (t3|s3|t4|s4)
    //   M16    [1703936, 68812800)            fp16 2x4096x4096
    //   MT16   [68812800, 135921664)          fp16 transpose
    //   planes [135921664, 186253312)         per-batch fp16: t3|s3|t4|s4
    float* inv = (float*)base;
    float* part = (float*)(base + 131072);
    _Float16* M16 = (_Float16*)(base + 1703936);
    _Float16* MT16 = (_Float16*)(base + 68812800);
    _Float16* P = (_Float16*)(base + 135921664);

    dim3 gg(32, 32);
    for (int b = 0; b < 2; ++b) {
        transpose_b<<<6144, 256, 0, stream>>>(s3, t3, s4, t4, P, part, b);
        norm_finalize_b<<<64, 256, 0, stream>>>(part, inv, b);
        corr_fused<<<gg, 256, 0, stream>>>(P, P + 4194304, P + 8388608, P + 16777216,
                                           inv + 8192, inv + 0, inv + 24576, inv + 16384,
                                           M16, MT16, b);
    }

    dim3 rg(4096, 2, 2);
    soft_argmax<<<rg, 256, 0, stream>>>(M16, MT16, out, s3, t3, s4, t4, inv);
}